// Round 1
// baseline (419.431 us; speedup 1.0000x reference)
//
#include <hip/hip_runtime.h>
#include <math.h>

#define BB 256
#define LL 512
#define DD 1024
#define NW 16   // waves per block (1024 threads)

// ---------------------------------------------------------------------------
// One block per doc, 1024 threads = 16 waves. Three phases, block-local:
//   P1: h = mean_l emb[tok_l]          (16 waves x 32 rows, 16 row streams/CU)
//   P2: q[d] = W[d,:] . h              (wave w owns d in [w*64, w*64+64))
//   P3: online-softmax attention + ct  (16 waves x 32 rows, reg-resident q)
// hidden/q never touch HBM; ctp/part share one 64 KB LDS buffer.
// ---------------------------------------------------------------------------
__global__ __launch_bounds__(1024) void k_fused(const int* __restrict__ tokens,
                                                const float* __restrict__ emb,
                                                const float* __restrict__ W,
                                                float* __restrict__ out) {
    __shared__ int   toks[LL];         // row byte-offsets/4 (pre-scaled by DD)
    __shared__ float part[NW][DD];     // P1 partial sums, reused as P3 ct partials
    __shared__ float hbuf[DD];
    __shared__ float qbuf[DD];
    __shared__ float mw[NW], sw[NW];

    const int b    = blockIdx.x;
    const int tid  = threadIdx.x;
    const int w    = tid >> 6;
    const int lane = tid & 63;
    const int off0 = lane * 4;

    if (tid < LL) toks[tid] = (tokens[b * LL + tid] + 1) * DD;
    __syncthreads();

    // ---------------- Phase 1: h = mean of gathered rows -------------------
    {
        float4 a0 = make_float4(0.f, 0.f, 0.f, 0.f);
        float4 a1 = a0, a2 = a0, a3 = a0;
        #pragma unroll 2
        for (int i = 0; i < 32; ++i) {
            const float* r = emb + toks[w * 32 + i] + off0;
            const float4 e0 = *(const float4*)(r);
            const float4 e1 = *(const float4*)(r + 256);
            const float4 e2 = *(const float4*)(r + 512);
            const float4 e3 = *(const float4*)(r + 768);
            a0.x += e0.x; a0.y += e0.y; a0.z += e0.z; a0.w += e0.w;
            a1.x += e1.x; a1.y += e1.y; a1.z += e1.z; a1.w += e1.w;
            a2.x += e2.x; a2.y += e2.y; a2.z += e2.z; a2.w += e2.w;
            a3.x += e3.x; a3.y += e3.y; a3.z += e3.z; a3.w += e3.w;
        }
        *(float4*)(&part[w][off0      ]) = a0;
        *(float4*)(&part[w][off0 + 256]) = a1;
        *(float4*)(&part[w][off0 + 512]) = a2;
        *(float4*)(&part[w][off0 + 768]) = a3;
    }
    __syncthreads();
    {
        float s = 0.f;
        #pragma unroll
        for (int j = 0; j < NW; ++j) s += part[j][tid];
        hbuf[tid] = s * (1.0f / (float)LL);
    }
    __syncthreads();

    // ---------------- Phase 2: q[d] = W[d,:] . h  (h in registers) ---------
    {
        const float4 h0 = *(const float4*)(&hbuf[off0      ]);
        const float4 h1 = *(const float4*)(&hbuf[off0 + 256]);
        const float4 h2 = *(const float4*)(&hbuf[off0 + 512]);
        const float4 h3 = *(const float4*)(&hbuf[off0 + 768]);

        for (int i = 0; i < 64; i += 2) {
            const int d0 = w * 64 + i;
            const float* r0 = W + (size_t)d0 * DD + off0;
            const float* r1 = r0 + DD;

            float4 v;
            float p0 = 0.f, p1 = 0.f;
            v = *(const float4*)(r0      ); p0 += v.x*h0.x + v.y*h0.y + v.z*h0.z + v.w*h0.w;
            v = *(const float4*)(r0 + 256); p0 += v.x*h1.x + v.y*h1.y + v.z*h1.z + v.w*h1.w;
            v = *(const float4*)(r0 + 512); p0 += v.x*h2.x + v.y*h2.y + v.z*h2.z + v.w*h2.w;
            v = *(const float4*)(r0 + 768); p0 += v.x*h3.x + v.y*h3.y + v.z*h3.z + v.w*h3.w;
            v = *(const float4*)(r1      ); p1 += v.x*h0.x + v.y*h0.y + v.z*h0.z + v.w*h0.w;
            v = *(const float4*)(r1 + 256); p1 += v.x*h1.x + v.y*h1.y + v.z*h1.z + v.w*h1.w;
            v = *(const float4*)(r1 + 512); p1 += v.x*h2.x + v.y*h2.y + v.z*h2.z + v.w*h2.w;
            v = *(const float4*)(r1 + 768); p1 += v.x*h3.x + v.y*h3.y + v.z*h3.z + v.w*h3.w;

            #pragma unroll
            for (int m = 32; m; m >>= 1) {
                p0 += __shfl_xor(p0, m, 64);
                p1 += __shfl_xor(p1, m, 64);
            }
            if (lane == 0) {
                qbuf[d0]     = p0;
                qbuf[d0 + 1] = p1;
            }
        }
    }
    __syncthreads();

    // ---------------- Phase 3: online softmax + context --------------------
    const float4 q0 = *(const float4*)(&qbuf[off0      ]);
    const float4 q1 = *(const float4*)(&qbuf[off0 + 256]);
    const float4 q2 = *(const float4*)(&qbuf[off0 + 512]);
    const float4 q3 = *(const float4*)(&qbuf[off0 + 768]);

    float m = -1e30f, s = 0.f;
    float4 c0 = make_float4(0.f, 0.f, 0.f, 0.f);
    float4 c1 = c0, c2 = c0, c3 = c0;

    #pragma unroll 2
    for (int i = 0; i < 32; ++i) {
        const float* r = emb + toks[w * 32 + i] + off0;
        const float4 e0 = *(const float4*)(r);
        const float4 e1 = *(const float4*)(r + 256);
        const float4 e2 = *(const float4*)(r + 512);
        const float4 e3 = *(const float4*)(r + 768);

        float p = e0.x*q0.x + e0.y*q0.y + e0.z*q0.z + e0.w*q0.w
                + e1.x*q1.x + e1.y*q1.y + e1.z*q1.z + e1.w*q1.w
                + e2.x*q2.x + e2.y*q2.y + e2.z*q2.z + e2.w*q2.w
                + e3.x*q3.x + e3.y*q3.y + e3.z*q3.z + e3.w*q3.w;
        #pragma unroll
        for (int mm = 32; mm; mm >>= 1) p += __shfl_xor(p, mm, 64);

        const float nm = fmaxf(m, p);
        const float f  = __expf(m - nm);
        const float we = __expf(p - nm);
        s = s * f + we;
        c0.x = c0.x * f + we * e0.x; c0.y = c0.y * f + we * e0.y;
        c0.z = c0.z * f + we * e0.z; c0.w = c0.w * f + we * e0.w;
        c1.x = c1.x * f + we * e1.x; c1.y = c1.y * f + we * e1.y;
        c1.z = c1.z * f + we * e1.z; c1.w = c1.w * f + we * e1.w;
        c2.x = c2.x * f + we * e2.x; c2.y = c2.y * f + we * e2.y;
        c2.z = c2.z * f + we * e2.z; c2.w = c2.w * f + we * e2.w;
        c3.x = c3.x * f + we * e3.x; c3.y = c3.y * f + we * e3.y;
        c3.z = c3.z * f + we * e3.z; c3.w = c3.w * f + we * e3.w;
        m = nm;
    }

    // part[] was fully consumed before the last __syncthreads(); reuse as ctp
    *(float4*)(&part[w][off0      ]) = c0;
    *(float4*)(&part[w][off0 + 256]) = c1;
    *(float4*)(&part[w][off0 + 512]) = c2;
    *(float4*)(&part[w][off0 + 768]) = c3;
    if (lane == 0) { mw[w] = m; sw[w] = s; }
    __syncthreads();

    // merge 16 wave-partials; each thread finalizes one d = tid
    float M = -1e30f;
    #pragma unroll
    for (int j = 0; j < NW; ++j) M = fmaxf(M, mw[j]);
    float denom = 0.f, sc[NW];
    #pragma unroll
    for (int j = 0; j < NW; ++j) { sc[j] = __expf(mw[j] - M); denom += sc[j] * sw[j]; }
    const float inv = 1.0f / denom;

    float acc = 0.f;
    #pragma unroll
    for (int j = 0; j < NW; ++j) acc += sc[j] * part[j][tid];
    out[b * DD + tid] = acc * inv;
}

// ---------------------------------------------------------------------------
extern "C" void kernel_launch(void* const* d_in, const int* in_sizes, int n_in,
                              void* d_out, int out_size, void* d_ws, size_t ws_size,
                              hipStream_t stream) {
    const int*   tokens = (const int*)d_in[0];
    // d_in[1] = max_len (scalar), fixed to LL
    const float* emb    = (const float*)d_in[2];
    const float* W      = (const float*)d_in[3];
    float*       out    = (float*)d_out;

    k_fused<<<BB, 1024, 0, stream>>>(tokens, emb, W, out);
}

// Round 2
// 406.673 us; speedup vs baseline: 1.0314x; 1.0314x over previous
//
#include <hip/hip_runtime.h>
#include <math.h>

#define BB 256
#define LL 512
#define DD 1024
#define NW 16   // waves per 1024-thread block

// ---------------------------------------------------------------------------
// Kernel 1: hidden[b,:] = (1/L) * sum_l emb[tok[b,l]+1, :]
// One block per doc, 16 waves x 32 rows, 4-row-batched float4 gather
// (16 outstanding float4 loads per wave) then LDS merge of 16 partials.
// ---------------------------------------------------------------------------
__global__ __launch_bounds__(1024) void k_hidden(const int* __restrict__ tokens,
                                                 const float* __restrict__ emb,
                                                 float* __restrict__ hidden) {
    __shared__ int   toks[LL];
    __shared__ float part[NW][DD];   // 64 KB

    const int b    = blockIdx.x;
    const int tid  = threadIdx.x;
    const int w    = tid >> 6;
    const int lane = tid & 63;
    const int off0 = lane * 4;

    if (tid < LL) toks[tid] = (tokens[b * LL + tid] + 1) * DD;
    __syncthreads();

    float4 a0 = make_float4(0.f, 0.f, 0.f, 0.f);
    float4 a1 = a0, a2 = a0, a3 = a0;

    for (int i = 0; i < 32; i += 4) {
        const float* r0 = emb + toks[w * 32 + i + 0] + off0;
        const float* r1 = emb + toks[w * 32 + i + 1] + off0;
        const float* r2 = emb + toks[w * 32 + i + 2] + off0;
        const float* r3 = emb + toks[w * 32 + i + 3] + off0;

        const float4 e00 = *(const float4*)(r0      );
        const float4 e01 = *(const float4*)(r0 + 256);
        const float4 e02 = *(const float4*)(r0 + 512);
        const float4 e03 = *(const float4*)(r0 + 768);
        const float4 e10 = *(const float4*)(r1      );
        const float4 e11 = *(const float4*)(r1 + 256);
        const float4 e12 = *(const float4*)(r1 + 512);
        const float4 e13 = *(const float4*)(r1 + 768);
        const float4 e20 = *(const float4*)(r2      );
        const float4 e21 = *(const float4*)(r2 + 256);
        const float4 e22 = *(const float4*)(r2 + 512);
        const float4 e23 = *(const float4*)(r2 + 768);
        const float4 e30 = *(const float4*)(r3      );
        const float4 e31 = *(const float4*)(r3 + 256);
        const float4 e32 = *(const float4*)(r3 + 512);
        const float4 e33 = *(const float4*)(r3 + 768);

        a0.x += e00.x + e10.x + e20.x + e30.x;
        a0.y += e00.y + e10.y + e20.y + e30.y;
        a0.z += e00.z + e10.z + e20.z + e30.z;
        a0.w += e00.w + e10.w + e20.w + e30.w;
        a1.x += e01.x + e11.x + e21.x + e31.x;
        a1.y += e01.y + e11.y + e21.y + e31.y;
        a1.z += e01.z + e11.z + e21.z + e31.z;
        a1.w += e01.w + e11.w + e21.w + e31.w;
        a2.x += e02.x + e12.x + e22.x + e32.x;
        a2.y += e02.y + e12.y + e22.y + e32.y;
        a2.z += e02.z + e12.z + e22.z + e32.z;
        a2.w += e02.w + e12.w + e22.w + e32.w;
        a3.x += e03.x + e13.x + e23.x + e33.x;
        a3.y += e03.y + e13.y + e23.y + e33.y;
        a3.z += e03.z + e13.z + e23.z + e33.z;
        a3.w += e03.w + e13.w + e23.w + e33.w;
    }

    *(float4*)(&part[w][off0      ]) = a0;
    *(float4*)(&part[w][off0 + 256]) = a1;
    *(float4*)(&part[w][off0 + 512]) = a2;
    *(float4*)(&part[w][off0 + 768]) = a3;
    __syncthreads();

    float s = 0.f;
    #pragma unroll
    for (int j = 0; j < NW; ++j) s += part[j][tid];
    hidden[b * DD + tid] = s * (1.0f / (float)LL);
}

// ---------------------------------------------------------------------------
// Kernel 2: q[b,d] = sum_e W[d,e] * hidden[b,e]
// grid (D/64, B/4), block 256 (4 waves). Each block: 4 docs x 64 W rows --
// W traffic amortized 4x (256 MB total), 4 blocks/CU for phase overlap.
// ---------------------------------------------------------------------------
__global__ __launch_bounds__(256) void k_q(const float* __restrict__ hidden,
                                           const float* __restrict__ W,
                                           float* __restrict__ q) {
    __shared__ float hs[4][DD];
    const int dt  = blockIdx.x;   // 0..15
    const int bt  = blockIdx.y;   // 0..63
    const int tid = threadIdx.x;

    #pragma unroll
    for (int j = 0; j < 4; ++j)
        #pragma unroll
        for (int k = 0; k < 4; ++k)
            hs[j][k * 256 + tid] = hidden[(bt * 4 + j) * DD + k * 256 + tid];
    __syncthreads();

    const int w = tid >> 6, lane = tid & 63;

    for (int i = 0; i < 16; ++i) {
        const int d = dt * 64 + w * 16 + i;
        float a0 = 0.f, a1 = 0.f, a2 = 0.f, a3 = 0.f;
        #pragma unroll
        for (int k = 0; k < 4; ++k) {
            const int off = k * 256 + lane * 4;
            const float4 wv = *(const float4*)(W + (size_t)d * DD + off);
            const float4 h0 = *(const float4*)(&hs[0][off]);
            const float4 h1 = *(const float4*)(&hs[1][off]);
            const float4 h2 = *(const float4*)(&hs[2][off]);
            const float4 h3 = *(const float4*)(&hs[3][off]);
            a0 += wv.x * h0.x + wv.y * h0.y + wv.z * h0.z + wv.w * h0.w;
            a1 += wv.x * h1.x + wv.y * h1.y + wv.z * h1.z + wv.w * h1.w;
            a2 += wv.x * h2.x + wv.y * h2.y + wv.z * h2.z + wv.w * h2.w;
            a3 += wv.x * h3.x + wv.y * h3.y + wv.z * h3.z + wv.w * h3.w;
        }
        #pragma unroll
        for (int m = 32; m; m >>= 1) {
            a0 += __shfl_xor(a0, m, 64);
            a1 += __shfl_xor(a1, m, 64);
            a2 += __shfl_xor(a2, m, 64);
            a3 += __shfl_xor(a3, m, 64);
        }
        if (lane == 0) {
            q[(bt * 4 + 0) * DD + d] = a0;
            q[(bt * 4 + 1) * DD + d] = a1;
            q[(bt * 4 + 2) * DD + d] = a2;
            q[(bt * 4 + 3) * DD + d] = a3;
        }
    }
}

// ---------------------------------------------------------------------------
// Kernel 3: fused scores -> online softmax -> ct. One block per doc,
// 16 waves x 32 rows, 2-row batching: paired shuffle chains + one
// max3/rescale per pair (halves the serial softmax chain).
// ---------------------------------------------------------------------------
__global__ __launch_bounds__(1024) void k_attn(const int* __restrict__ tokens,
                                               const float* __restrict__ emb,
                                               const float* __restrict__ q,
                                               float* __restrict__ out) {
    __shared__ int   toks[LL];
    __shared__ float ctp[NW][DD];   // 64 KB
    __shared__ float mw[NW], sw[NW];

    const int b    = blockIdx.x;
    const int tid  = threadIdx.x;
    const int w    = tid >> 6;
    const int lane = tid & 63;
    const int off0 = lane * 4;

    if (tid < LL) toks[tid] = (tokens[b * LL + tid] + 1) * DD;
    __syncthreads();

    float4 q0 = *(const float4*)(q + b * DD + off0      );
    float4 q1 = *(const float4*)(q + b * DD + off0 + 256);
    float4 q2 = *(const float4*)(q + b * DD + off0 + 512);
    float4 q3 = *(const float4*)(q + b * DD + off0 + 768);

    float m = -1e30f, s = 0.f;
    float4 c0 = make_float4(0.f, 0.f, 0.f, 0.f);
    float4 c1 = c0, c2 = c0, c3 = c0;

    for (int i = 0; i < 32; i += 2) {
        const float* ra = emb + toks[w * 32 + i    ] + off0;
        const float* rb = emb + toks[w * 32 + i + 1] + off0;
        const float4 a0 = *(const float4*)(ra      );
        const float4 a1 = *(const float4*)(ra + 256);
        const float4 a2 = *(const float4*)(ra + 512);
        const float4 a3 = *(const float4*)(ra + 768);
        const float4 b0 = *(const float4*)(rb      );
        const float4 b1 = *(const float4*)(rb + 256);
        const float4 b2 = *(const float4*)(rb + 512);
        const float4 b3 = *(const float4*)(rb + 768);

        float p0 = a0.x*q0.x + a0.y*q0.y + a0.z*q0.z + a0.w*q0.w
                 + a1.x*q1.x + a1.y*q1.y + a1.z*q1.z + a1.w*q1.w
                 + a2.x*q2.x + a2.y*q2.y + a2.z*q2.z + a2.w*q2.w
                 + a3.x*q3.x + a3.y*q3.y + a3.z*q3.z + a3.w*q3.w;
        float p1 = b0.x*q0.x + b0.y*q0.y + b0.z*q0.z + b0.w*q0.w
                 + b1.x*q1.x + b1.y*q1.y + b1.z*q1.z + b1.w*q1.w
                 + b2.x*q2.x + b2.y*q2.y + b2.z*q2.z + b2.w*q2.w
                 + b3.x*q3.x + b3.y*q3.y + b3.z*q3.z + b3.w*q3.w;

        #pragma unroll
        for (int mm = 32; mm; mm >>= 1) {
            p0 += __shfl_xor(p0, mm, 64);
            p1 += __shfl_xor(p1, mm, 64);
        }

        const float nm = fmaxf(m, fmaxf(p0, p1));   // v_max3
        const float f  = __expf(m - nm);
        const float w0 = __expf(p0 - nm);
        const float w1 = __expf(p1 - nm);
        s = s * f + w0 + w1;
        c0.x = c0.x * f + w0 * a0.x + w1 * b0.x;
        c0.y = c0.y * f + w0 * a0.y + w1 * b0.y;
        c0.z = c0.z * f + w0 * a0.z + w1 * b0.z;
        c0.w = c0.w * f + w0 * a0.w + w1 * b0.w;
        c1.x = c1.x * f + w0 * a1.x + w1 * b1.x;
        c1.y = c1.y * f + w0 * a1.y + w1 * b1.y;
        c1.z = c1.z * f + w0 * a1.z + w1 * b1.z;
        c1.w = c1.w * f + w0 * a1.w + w1 * b1.w;
        c2.x = c2.x * f + w0 * a2.x + w1 * b2.x;
        c2.y = c2.y * f + w0 * a2.y + w1 * b2.y;
        c2.z = c2.z * f + w0 * a2.z + w1 * b2.z;
        c2.w = c2.w * f + w0 * a2.w + w1 * b2.w;
        c3.x = c3.x * f + w0 * a3.x + w1 * b3.x;
        c3.y = c3.y * f + w0 * a3.y + w1 * b3.y;
        c3.z = c3.z * f + w0 * a3.z + w1 * b3.z;
        c3.w = c3.w * f + w0 * a3.w + w1 * b3.w;
        m = nm;
    }

    *(float4*)(&ctp[w][off0      ]) = c0;
    *(float4*)(&ctp[w][off0 + 256]) = c1;
    *(float4*)(&ctp[w][off0 + 512]) = c2;
    *(float4*)(&ctp[w][off0 + 768]) = c3;
    if (lane == 0) { mw[w] = m; sw[w] = s; }
    __syncthreads();

    float M = -1e30f;
    #pragma unroll
    for (int j = 0; j < NW; ++j) M = fmaxf(M, mw[j]);
    float denom = 0.f, sc[NW];
    #pragma unroll
    for (int j = 0; j < NW; ++j) { sc[j] = __expf(mw[j] - M); denom += sc[j] * sw[j]; }
    const float inv = 1.0f / denom;

    float acc = 0.f;
    #pragma unroll
    for (int j = 0; j < NW; ++j) acc += sc[j] * ctp[j][tid];
    out[b * DD + tid] = acc * inv;
}

// ---------------------------------------------------------------------------
extern "C" void kernel_launch(void* const* d_in, const int* in_sizes, int n_in,
                              void* d_out, int out_size, void* d_ws, size_t ws_size,
                              hipStream_t stream) {
    const int*   tokens = (const int*)d_in[0];
    // d_in[1] = max_len (scalar), fixed to LL
    const float* emb    = (const float*)d_in[2];
    const float* W      = (const float*)d_in[3];
    float*       out    = (float*)d_out;

    float* hidden = (float*)d_ws;           // BB*DD floats = 1 MB
    float* q      = hidden + BB * DD;       // BB*DD floats = 1 MB

    k_hidden<<<BB, 1024, 0, stream>>>(tokens, emb, hidden);
    dim3 g2(DD / 64, BB / 4);
    k_q<<<g2, 256, 0, stream>>>(hidden, W, q);
    k_attn<<<BB, 1024, 0, stream>>>(tokens, emb, q, out);
}